// Round 11
// baseline (248.940 us; speedup 1.0000x reference)
//
#include <hip/hip_runtime.h>
#include <stdint.h>

// ---------------------------------------------------------------------------
// VectorQuantizer: argmin_k ||x_n - c_k||^2 + straight-through out + losses.
//
// Token semantics (R4/R5/R7/R9-verified): candidates by continuous score
// s = ||c||^2 - 2 x.c via fp16 MFMA; exact fp64 re-score; token = lowest
// index within 0.75*ulp_fp32(Dmin) of the minimum.
//
// R15: swizzled global_load_lds dbuf B (103us). R16: A panel in 128 VGPRs
// (74us, occ 20%). R17: lane-parallel refine (total 203us). R18-R21:
// counted-vmcnt pipeline arc -- R21 finally clean (zero epilogue VMEM,
// uniform loop) and NULL: 75us == R16. Schedule is not the constraint;
// occupancy (2 waves/SIMD, reg-pinned by afr128+acc64=192) is.
// R22: half-A-panel for occupancy. afr[4][4] (64 VGPR) holding one
//   dc-half, reloaded from L2 per half-kt (A re-read 256KB/block from
//   L2/L3; latency inside the step sync / covered by extra wave).
//   Proven R16 __syncthreads 2-buffer schedule. (256,3): ~163 regs <=
//   170 cap, LDS 52.5KB x3 = 157.5 <= 160KB -> 3 blocks/CU = 12
//   waves/CU (+50% TLP). R13's goal minus R13's killers (no persistent
//   pipeline regs; swizzled conflict-free staging).
//   + vq_final 16 -> 64 blocks (4-way rb-split, coalesced).
// ---------------------------------------------------------------------------

#define N_ROWS 16384
#define DIM    256
#define KCODES 4096
#define NCHUNK 8
#define KC     (KCODES / NCHUNK)   // 512 codes per chunk
#define TM     128                 // rows per block tile
#define TN     128                 // codes per code-tile
#define BK     32                  // K per dc step
#define NKT    (KC / TN)           // 4 code tiles per chunk
#define NDC    (DIM / BK)          // 8 K-steps
#define NSTEP  (NKT * NDC)         // 32 pipeline steps
#define NGRAN  (NCHUNK * 2)        // 16 granules of 256 cols (chunk x chalf)
#define NRB    (N_ROWS / TM)       // 128 row-blocks

typedef float    f32x4 __attribute__((ext_vector_type(4)));
typedef _Float16 f16x8 __attribute__((ext_vector_type(8)));

#define GLOAD_LDS16(g, l) __builtin_amdgcn_global_load_lds(                 \
    (const __attribute__((address_space(1))) void*)(g),                     \
    (__attribute__((address_space(3))) void*)(l), 16, 0, 0)

__device__ __forceinline__ unsigned umin_(unsigned a, unsigned b) { return a < b ? a : b; }
__device__ __forceinline__ unsigned umax_(unsigned a, unsigned b) { return a > b ? a : b; }
__device__ __forceinline__ unsigned long long umin64_(unsigned long long a,
                                                      unsigned long long b) {
    return a < b ? a : b;
}
__device__ __forceinline__ unsigned long long umax64_(unsigned long long a,
                                                      unsigned long long b) {
    return a > b ? a : b;
}

// order-preserving float->uint key
__device__ __forceinline__ unsigned fkey(float f) {
    unsigned b = __float_as_uint(f);
    return (b & 0x80000000u) ? ~b : (b | 0x80000000u);
}
__device__ __forceinline__ float fkey_inv(unsigned k) {
    unsigned b = (k & 0x80000000u) ? (k ^ 0x80000000u) : ~k;
    return __uint_as_float(b);
}
__device__ __forceinline__ unsigned short f2h(float f) {
    union { _Float16 h; unsigned short u; } cv;
    cv.h = (_Float16)f;            // v_cvt_f16_f32, RNE
    return cv.u;
}

// ---- prep: fp16 cast + row sumsq (fp64->fp32) + buffer init, fused ----
__global__ __launch_bounds__(256) void vq_prep_kernel(
        const float* __restrict__ x, const float* __restrict__ cb,
        unsigned short* __restrict__ xh, unsigned short* __restrict__ ch,
        float* __restrict__ xsq, float* __restrict__ csq,
        unsigned* __restrict__ active, double* __restrict__ accum,
        unsigned* __restrict__ counter) {
    const int b = blockIdx.x, t = threadIdx.x;
    if (b < KCODES / 256) {
        int i = b * 256 + t;
        active[i] = 0u;
        if (i == 0) { accum[0] = 0.0; accum[1] = 0.0; counter[0] = 0u; }
    }
    const size_t NX = (size_t)N_ROWS * DIM;
    size_t e = (size_t)b * 1024 + (size_t)t * 4;
    const float* src; unsigned short* dst; float* sq; size_t off;
    if (e < NX) { src = x;  dst = xh; sq = xsq; off = e; }
    else        { src = cb; dst = ch; sq = csq; off = e - NX; }
    float4 v = *(const float4*)(src + off);
    ushort4 h;
    h.x = f2h(v.x); h.y = f2h(v.y); h.z = f2h(v.z); h.w = f2h(v.w);
    *(ushort4*)(dst + off) = h;
    double s = (double)v.x * v.x + (double)v.y * v.y
             + (double)v.z * v.z + (double)v.w * v.w;
    for (int o = 32; o; o >>= 1) s += __shfl_down(s, o);
    if ((t & 63) == 0) sq[off >> 8] = (float)s;
}

// ---- MFMA candidate GEMM. grid = (NRB, NCHUNK), 256 thr (4 waves).
// Half A-panel in regs (reloaded per half-kt); B via swizzled
// global_load_lds dbuf; proven __syncthreads schedule; (256,3).
__global__ __launch_bounds__(256, 3) void vq_gemm_kernel(
        const unsigned short* __restrict__ xh_g, const unsigned short* __restrict__ ch_g,
        const float* __restrict__ xsq, const float* __restrict__ csq,
        unsigned* __restrict__ colmin_part, uint2* __restrict__ top2_out) {
    __shared__ __align__(16) unsigned short b_lds[2][TN][BK];  // 16 KB
    __shared__ float    xsq_l[128];
    __shared__ float    csq_l[KC];        // 2 KB: epilogue is lgkm-only
    __shared__ unsigned colmin_l[KC];
    __shared__ uint2    u12_l[16][256];   // 32 KB: per-thread top-2 state

    const int t = threadIdx.x;
    const int wave = t >> 6, lane = t & 63, quad = lane >> 4, L = lane & 15;
    const int whalf = wave >> 1, chalf = wave & 1;
    const int row0  = blockIdx.x * TM;
    const int code0 = blockIdx.y * KC;

    if (t < 128) xsq_l[t] = xsq[row0 + t];
    csq_l[t]       = csq[code0 + t];
    csq_l[t + 256] = csq[code0 + t + 256];
    colmin_l[t] = 0xFFFFFFFFu; colmin_l[t + 256] = 0xFFFFFFFFu;
#pragma unroll
    for (int i = 0; i < 16; ++i)
        u12_l[i][t] = make_uint2(0xFFFFFFFFu, 0xFFFFFFFFu);

    const unsigned short* abase =
        xh_g + ((size_t)(row0 + whalf * 64 + L) * DIM + quad * 8);

    // Staging (swizzled): LDS 16B-chunk j holds global (row j>>2,
    // slot (j&3)^((j>>3)&3)) -- slot t at row r carries global slot
    // t^((r>>1)&3), an involution. Linear LDS dest per DMA semantics.
    auto stageB = [&](int buf, int kt_, int dc_) {
        const unsigned short* bsrc =
            ch_g + (size_t)(code0 + kt_ * TN) * DIM + dc_ * BK;
        unsigned short* dst = &b_lds[buf][0][0];
#pragma unroll
        for (int k = 0; k < 2; ++k) {
            const int j = t + k * 256;
            const int r = j >> 2, sg = (j & 3) ^ ((j >> 3) & 3);
            GLOAD_LDS16(bsrc + (size_t)r * DIM + sg * 8, dst + (size_t)j * 8);
        }
    };

    const int bslot = (L >> 1) & 3;     // read-side swizzle term

    // half A-panel: 16 fragments (64 VGPR), compile-time indexed
    f16x8 afr[4][4];
    auto loadA = [&](int h) {
#pragma unroll
        for (int i = 0; i < 4; ++i)
#pragma unroll
            for (int mt = 0; mt < 4; ++mt)
                afr[i][mt] = *(const f16x8*)(abase + (size_t)mt * 16 * DIM
                                             + (h * 4 + i) * BK);
    };

    // prologue: first B slice in flight
    stageB(0, 0, 0);

    // epilogue (per kt): packed-key top-2 upkeep + column-min. All inputs
    // in LDS/regs (no VMEM).
    auto epilogue = [&](int kt, f32x4 (&acc)[4][4]) {
        float csq4[4]; unsigned colf[4];
        float dmin[4] = {3.4e38f, 3.4e38f, 3.4e38f, 3.4e38f};
#pragma unroll
        for (int nt = 0; nt < 4; ++nt) {
            csq4[nt] = csq_l[kt * TN + chalf * 64 + nt * 16 + L];
            colf[nt] = (unsigned)(kt * 128 + chalf * 64 + nt * 16 + L);
        }
#pragma unroll
        for (int mt = 0; mt < 4; ++mt) {
            const f32x4 xq = *(const f32x4*)&xsq_l[whalf * 64 + mt * 16 + quad * 4];
#pragma unroll
            for (int reg = 0; reg < 4; ++reg) {
                const int i = mt * 4 + reg;
                uint2 e = u12_l[i][t];
#pragma unroll
                for (int nt = 0; nt < 4; ++nt) {
                    float s = fmaf(-2.0f, acc[mt][nt][reg], csq4[nt]);
                    unsigned key = (fkey(s) & 0xFFFFFE00u) | colf[nt];
                    unsigned lo = umin_(e.x, key);
                    e.y = umin_(e.y, umax_(e.x, key));
                    e.x = lo;
                    dmin[nt] = fminf(dmin[nt], xq[reg] + s);
                }
                u12_l[i][t] = e;
            }
        }
#pragma unroll
        for (int nt = 0; nt < 4; ++nt) {
            unsigned dk = fkey(dmin[nt]);
            dk = umin_(dk, (unsigned)__shfl_xor((int)dk, 16));
            dk = umin_(dk, (unsigned)__shfl_xor((int)dk, 32));
            if (quad == 0)
                atomicMin(&colmin_l[kt * TN + chalf * 64 + nt * 16 + L], dk);
        }
    };

    for (int kt = 0; kt < NKT; ++kt) {
        f32x4 acc[4][4];
#pragma unroll
        for (int mt = 0; mt < 4; ++mt)
#pragma unroll
            for (int nt = 0; nt < 4; ++nt) acc[mt][nt] = (f32x4){0.f, 0.f, 0.f, 0.f};

        loadA(0);                            // dc 0-3 fragments
#pragma unroll
        for (int dc = 0; dc < 4; ++dc) {
            const int cur = dc & 1;
            __syncthreads();                 // buf[cur] staged; prior reads done
            const int s = kt * NDC + dc;
            if (s < NSTEP - 1)
                stageB(cur ^ 1, kt + (dc == NDC - 1), (dc + 1) & 7);
            f16x8 bf[4];
#pragma unroll
            for (int nt = 0; nt < 4; ++nt)
                bf[nt] = *(const f16x8*)
                    &b_lds[cur][chalf * 64 + nt * 16 + L][(quad ^ bslot) * 8];
#pragma unroll
            for (int mt = 0; mt < 4; ++mt)
#pragma unroll
                for (int nt = 0; nt < 4; ++nt)
                    acc[mt][nt] = __builtin_amdgcn_mfma_f32_16x16x32_f16(
                        afr[dc][mt], bf[nt], acc[mt][nt], 0, 0, 0);
        }
        loadA(1);                            // dc 4-7 fragments (reuse regs)
#pragma unroll
        for (int dc = 4; dc < 8; ++dc) {
            const int cur = dc & 1;
            __syncthreads();
            const int s = kt * NDC + dc;
            if (s < NSTEP - 1)
                stageB(cur ^ 1, kt + (dc == NDC - 1), (dc + 1) & 7);
            f16x8 bf[4];
#pragma unroll
            for (int nt = 0; nt < 4; ++nt)
                bf[nt] = *(const f16x8*)
                    &b_lds[cur][chalf * 64 + nt * 16 + L][(quad ^ bslot) * 8];
#pragma unroll
            for (int mt = 0; mt < 4; ++mt)
#pragma unroll
                for (int nt = 0; nt < 4; ++nt)
                    acc[mt][nt] = __builtin_amdgcn_mfma_f32_16x16x32_f16(
                        afr[dc - 4][mt], bf[nt], acc[mt][nt], 0, 0, 0);
        }
        epilogue(kt, acc);
    }

    // ---- once per block: butterfly-merge top-2 across the 16 L-lanes ----
    unsigned u1[16], u2[16];
#pragma unroll
    for (int i = 0; i < 16; ++i) {
        uint2 e = u12_l[i][t];
        u1[i] = e.x; u2[i] = e.y;
    }
#pragma unroll
    for (int i = 0; i < 16; ++i) {
#pragma unroll
        for (int st = 1; st < 16; st <<= 1) {
            unsigned w1 = (unsigned)__shfl_xor((int)u1[i], st);
            unsigned w2 = (unsigned)__shfl_xor((int)u2[i], st);
            unsigned a = umin_(u1[i], w1), b = umax_(u1[i], w1);
            u1[i] = a;
            u2[i] = umin_(umin_(u2[i], w2), b);
        }
    }
    if (L == 0) {
        const size_t gbase = (size_t)(blockIdx.y * 2 + chalf) * N_ROWS;
#pragma unroll
        for (int mt = 0; mt < 4; ++mt)
#pragma unroll
            for (int reg = 0; reg < 4; ++reg) {
                const int row = row0 + whalf * 64 + mt * 16 + quad * 4 + reg;
                top2_out[gbase + row] = make_uint2(u1[mt * 4 + reg], u2[mt * 4 + reg]);
            }
    }

    // ---- flush block-local colmin to private slice (plain stores) ----
    __syncthreads();
    unsigned* cp = colmin_part + (size_t)blockIdx.x * KCODES + code0;
    cp[t]       = colmin_l[t];
    cp[t + 256] = colmin_l[t + 256];
}

// ---- refine + gather + MSE, fused. grid = N_ROWS/4, 1 wave per row. ----
// R17: lane-parallel candidate selection (u64 key = score32|id32, same
// (v,id) lexicographic order). Fast path: (min1,min2) butterfly. Slow
// path: 8x extract-min recovers the identical top-8 set, then fp64
// re-score. R21: per-lane p[k]=cc2-2dd partials -> 9-value fp64 reduce.
__global__ __launch_bounds__(256) void vq_refine_kernel(
        const float* __restrict__ x, const float* __restrict__ cb,
        const uint2* __restrict__ top2, unsigned* __restrict__ active,
        float* __restrict__ out, double* __restrict__ accum) {
    __shared__ double wsum[4];
    const int wave = threadIdx.x >> 6, lane = threadIdx.x & 63;
    const int row  = blockIdx.x * 4 + wave;

    // lane-owned candidate -> packed u64 (quantized-score | id)
    const int g = (lane >> 1) & 15;
    uint2 e = top2[(size_t)g * N_ROWS + row];
    unsigned key = (lane & 1) ? e.y : e.x;
    unsigned idc = (unsigned)((g >> 1) * KC) + (key & 0x1FFu);
    unsigned long long pk =
        ((unsigned long long)(key & 0xFFFFFE00u) << 32) | idc;
    if (lane >= 32) pk = ~0ull;

    // butterfly (min1, min2) across 64 lanes -- wave-uniform result
    unsigned long long m1 = pk, m2 = ~0ull;
#pragma unroll
    for (int o = 1; o < 64; o <<= 1) {
        unsigned long long w1 = (unsigned long long)__shfl_xor((long long)m1, o);
        unsigned long long w2 = (unsigned long long)__shfl_xor((long long)m2, o);
        unsigned long long lo = umin64_(m1, w1), hi = umax64_(m1, w1);
        m1 = lo;
        m2 = umin64_(umin64_(m2, w2), hi);
    }
    const float v0 = fkey_inv((unsigned)(m1 >> 32));
    const float v1 = fkey_inv((unsigned)(m2 >> 32));

    float4 xv = ((const float4*)(x + (size_t)row * DIM))[lane];
    int tok;
    if (v1 > v0 + 1.0e-2f) {
        tok = (int)(unsigned)(m1 & 0xFFFFFFFFu);
    } else {
        // recover top-8 ids (ascending (v,id) order) by repeated extract-min
        int id8[8];
        unsigned long long cur = pk;
#pragma unroll
        for (int k = 0; k < 8; ++k) {
            unsigned long long m = cur;
#pragma unroll
            for (int o = 1; o < 64; o <<= 1)
                m = umin64_(m, (unsigned long long)__shfl_xor((long long)m, o));
            id8[k] = (int)(unsigned)(m & 0xFFFFFFFFu);
            if (cur == m) cur = ~0ull;   // owning lane removes it
        }

        double xs64 = (double)xv.x * xv.x + (double)xv.y * xv.y
                    + (double)xv.z * xv.z + (double)xv.w * xv.w;
        double p[8];
#pragma unroll
        for (int k = 0; k < 8; ++k) {
            float4 c4 = ((const float4*)(cb + (size_t)id8[k] * DIM))[lane];
            double dd  = (double)xv.x * c4.x + (double)xv.y * c4.y
                       + (double)xv.z * c4.z + (double)xv.w * c4.w;
            double cc2 = (double)c4.x * c4.x + (double)c4.y * c4.y
                       + (double)c4.z * c4.z + (double)c4.w * c4.w;
            p[k] = cc2 - 2.0 * dd;       // per-lane partial of cc2 - 2 x.c
        }
#pragma unroll
        for (int o = 32; o; o >>= 1) {
            xs64 += __shfl_down(xs64, o);
#pragma unroll
            for (int k = 0; k < 8; ++k)
                p[k] += __shfl_down(p[k], o);
        }
        if (lane == 0) {
            double D[8], Dmin = 1e300;
#pragma unroll
            for (int k = 0; k < 8; ++k) {
                D[k] = xs64 + p[k];
                Dmin = fmin(Dmin, D[k]);
            }
            int e2; frexp(Dmin, &e2);
            double U   = ldexp(1.0, e2 - 1 - 23);     // ulp_fp32(Dmin)
            double thr = Dmin + 0.75 * U;
            tok = 0x7FFFFFFF;
#pragma unroll
            for (int k = 0; k < 8; ++k)
                if (D[k] <= thr && id8[k] < tok) tok = id8[k];
        }
        tok = __shfl(tok, 0);
    }

    if (lane == 0) active[tok] = 1u;
    float4 sel = ((const float4*)(cb + (size_t)tok * DIM))[lane];
    ((float4*)out)[(size_t)row * 64 + lane] = sel;
    float dx = sel.x - xv.x, dy = sel.y - xv.y, dz = sel.z - xv.z, dw = sel.w - xv.w;
    float s = dx * dx + dy * dy + dz * dz + dw * dw;
    for (int o = 32; o; o >>= 1) s += __shfl_down(s, o);
    if (lane == 0) wsum[wave] = (double)s;
    __syncthreads();
    if (threadIdx.x == 0) atomicAdd(accum, wsum[0] + wsum[1] + wsum[2] + wsum[3]);
}

// ---- final: 128-way colmin reduction + entropy + loss. grid = 64 blocks.
// R22: 64 codes/block x 4-way rb split (coalesced 256B chunks), 4x the
// parallelism of the old 16-block version; 64th finisher computes loss.
__global__ __launch_bounds__(256) void vq_final_kernel(
        const unsigned* __restrict__ colmin_part, const unsigned* __restrict__ active,
        double* __restrict__ accum, unsigned* __restrict__ counter,
        float* __restrict__ out) {
    __shared__ unsigned pmin[4][64];
    __shared__ double red[64];
    const int t = threadIdx.x;
    const int cl = t & 63, part = t >> 6;     // 64 codes x 4 rb-parts
    const int c = blockIdx.x * 64 + cl;
    unsigned m = 0xFFFFFFFFu;
#pragma unroll 8
    for (int rb = part * 32; rb < part * 32 + 32; ++rb)
        m = umin_(m, colmin_part[(size_t)rb * KCODES + c]);
    pmin[part][cl] = m;
    __syncthreads();
    if (part == 0) {
        m = umin_(umin_(pmin[0][cl], pmin[1][cl]),
                  umin_(pmin[2][cl], pmin[3][cl]));
        red[cl] = (active[c] == 0u) ? (double)fkey_inv(m) : 0.0;
    }
    __syncthreads();
    if (t < 64) {
        double s = red[t];
        for (int o = 32; o; o >>= 1) s += __shfl_down(s, o);
        if (t == 0) {
            atomicAdd(&accum[1], s);
            __threadfence();
            unsigned old = atomicAdd(counter, 1u);
            if (old == 63u) {
                __threadfence();
                double ent = atomicAdd(&accum[1], 0.0);   // atomic read
                double loss = 1.25 * (accum[0] / (double)((size_t)N_ROWS * DIM))
                            + 0.02 * (ent / (double)KCODES);
                out[(size_t)N_ROWS * DIM] = (float)loss;
            }
        }
    }
}

extern "C" void kernel_launch(void* const* d_in, const int* in_sizes, int n_in,
                              void* d_out, int out_size, void* d_ws, size_t ws_size,
                              hipStream_t stream) {
    const float* x  = (const float*)d_in[0];   // [16384, 256]
    const float* cb = (const float*)d_in[1];   // [4096, 256]
    float* out = (float*)d_out;                // [16384*256] ++ [1] loss

    char* ws = (char*)d_ws;
    float*    xsq     = (float*)(ws + 0);                      // 64 KB
    float*    csq     = (float*)(ws + 65536);                  // 16 KB
    unsigned* active  = (unsigned*)(ws + 81920);               // 16 KB
    double*   accum   = (double*)(ws + 98304);                 // 256 B (mse, entropy)
    unsigned* counter = (unsigned*)(ws + 98560);               // 64 B
    uint2*    top2    = (uint2*)(ws + 131072);                 // 2 MB (16 granules)
    unsigned* cpart   = (unsigned*)(ws + 2228224);             // 2 MB (128 x 4096)
    unsigned short* xh_g = (unsigned short*)(ws + 4325376);    // 8 MB
    unsigned short* ch_g = (unsigned short*)(ws + 12713984);   // 2 MB (~14.2 MB)

    vq_prep_kernel<<<((N_ROWS + KCODES) * DIM) / 1024, 256, 0, stream>>>(
        x, cb, xh_g, ch_g, xsq, csq, active, accum, counter);
    vq_gemm_kernel<<<dim3(NRB, NCHUNK), 256, 0, stream>>>(
        xh_g, ch_g, xsq, csq, cpart, top2);
    vq_refine_kernel<<<N_ROWS / 4, 256, 0, stream>>>(
        x, cb, top2, active, out, accum);
    vq_final_kernel<<<KCODES / 64, 256, 0, stream>>>(
        cpart, active, accum, counter, out);
}

// Round 12
// 199.436 us; speedup vs baseline: 1.2482x; 1.2482x over previous
//
#include <hip/hip_runtime.h>
#include <stdint.h>

// ---------------------------------------------------------------------------
// VectorQuantizer: argmin_k ||x_n - c_k||^2 + straight-through out + losses.
//
// Token semantics (R4/R5/R7/R9-verified): candidates by continuous score
// s = ||c||^2 - 2 x.c via fp16 MFMA; exact fp64 re-score; token = lowest
// index within 0.75*ulp_fp32(Dmin) of the minimum.
//
// Session arc: R15 swizzled global_load_lds dbuf B (103us gemm). R16 full
// A-panel in 128 VGPRs, (256,2) (74us gemm). R17 lane-parallel refine
// (total 203us). R18-R21 counted-vmcnt pipeline arc: NULL (74-75us across
// all clean variants) -- schedule is not the constraint at this structure.
// R22 half-A-panel at (256,3): allocator spilled (VGPR 84, WRITE 93MB) --
// third spill at 3 waves/SIMD (R13, R18, R22); occupancy lever closed.
// R23: consolidation of best-known pieces:
//   gemm   = R16/R17 exact (74us, measured twice)
//   refine = R21 (lane-parallel + 9-value fp64 reduce)
//   final  = R22 64-block (4-way rb-split, coalesced)
// ---------------------------------------------------------------------------

#define N_ROWS 16384
#define DIM    256
#define KCODES 4096
#define NCHUNK 8
#define KC     (KCODES / NCHUNK)   // 512 codes per chunk
#define TM     128                 // rows per block tile
#define TN     128                 // codes per code-tile
#define BK     32                  // K per dc step
#define NKT    (KC / TN)           // 4 code tiles per chunk
#define NDC    (DIM / BK)          // 8 K-steps
#define NSTEP  (NKT * NDC)         // 32 pipeline steps
#define NGRAN  (NCHUNK * 2)        // 16 granules of 256 cols (chunk x chalf)
#define NRB    (N_ROWS / TM)       // 128 row-blocks

typedef float    f32x4 __attribute__((ext_vector_type(4)));
typedef _Float16 f16x8 __attribute__((ext_vector_type(8)));

#define GLOAD_LDS16(g, l) __builtin_amdgcn_global_load_lds(                 \
    (const __attribute__((address_space(1))) void*)(g),                     \
    (__attribute__((address_space(3))) void*)(l), 16, 0, 0)

__device__ __forceinline__ unsigned umin_(unsigned a, unsigned b) { return a < b ? a : b; }
__device__ __forceinline__ unsigned umax_(unsigned a, unsigned b) { return a > b ? a : b; }
__device__ __forceinline__ unsigned long long umin64_(unsigned long long a,
                                                      unsigned long long b) {
    return a < b ? a : b;
}
__device__ __forceinline__ unsigned long long umax64_(unsigned long long a,
                                                      unsigned long long b) {
    return a > b ? a : b;
}

// order-preserving float->uint key
__device__ __forceinline__ unsigned fkey(float f) {
    unsigned b = __float_as_uint(f);
    return (b & 0x80000000u) ? ~b : (b | 0x80000000u);
}
__device__ __forceinline__ float fkey_inv(unsigned k) {
    unsigned b = (k & 0x80000000u) ? (k ^ 0x80000000u) : ~k;
    return __uint_as_float(b);
}
__device__ __forceinline__ unsigned short f2h(float f) {
    union { _Float16 h; unsigned short u; } cv;
    cv.h = (_Float16)f;            // v_cvt_f16_f32, RNE
    return cv.u;
}

// ---- prep: fp16 cast + row sumsq (fp64->fp32) + buffer init, fused ----
__global__ __launch_bounds__(256) void vq_prep_kernel(
        const float* __restrict__ x, const float* __restrict__ cb,
        unsigned short* __restrict__ xh, unsigned short* __restrict__ ch,
        float* __restrict__ xsq, float* __restrict__ csq,
        unsigned* __restrict__ active, double* __restrict__ accum,
        unsigned* __restrict__ counter) {
    const int b = blockIdx.x, t = threadIdx.x;
    if (b < KCODES / 256) {
        int i = b * 256 + t;
        active[i] = 0u;
        if (i == 0) { accum[0] = 0.0; accum[1] = 0.0; counter[0] = 0u; }
    }
    const size_t NX = (size_t)N_ROWS * DIM;
    size_t e = (size_t)b * 1024 + (size_t)t * 4;
    const float* src; unsigned short* dst; float* sq; size_t off;
    if (e < NX) { src = x;  dst = xh; sq = xsq; off = e; }
    else        { src = cb; dst = ch; sq = csq; off = e - NX; }
    float4 v = *(const float4*)(src + off);
    ushort4 h;
    h.x = f2h(v.x); h.y = f2h(v.y); h.z = f2h(v.z); h.w = f2h(v.w);
    *(ushort4*)(dst + off) = h;
    double s = (double)v.x * v.x + (double)v.y * v.y
             + (double)v.z * v.z + (double)v.w * v.w;
    for (int o = 32; o; o >>= 1) s += __shfl_down(s, o);
    if ((t & 63) == 0) sq[off >> 8] = (float)s;
}

// ---- MFMA candidate GEMM (R16/R17 exact, 74us). grid = (NRB, NCHUNK),
// 256 thr (4 waves). A panel persistent in 128 VGPRs; B via swizzled
// global_load_lds 2-buffer; __syncthreads schedule; (256,2).
__global__ __launch_bounds__(256, 2) void vq_gemm_kernel(
        const unsigned short* __restrict__ xh_g, const unsigned short* __restrict__ ch_g,
        const float* __restrict__ xsq, const float* __restrict__ csq,
        unsigned* __restrict__ colmin_part, uint2* __restrict__ top2_out) {
    __shared__ __align__(16) unsigned short b_lds[2][TN][BK];  // 16 KB
    __shared__ float    xsq_l[128];
    __shared__ unsigned colmin_l[KC];
    __shared__ uint2    u12_l[16][256];   // 32 KB: per-thread top-2 state

    const int t = threadIdx.x;
    const int wave = t >> 6, lane = t & 63, quad = lane >> 4, L = lane & 15;
    const int whalf = wave >> 1, chalf = wave & 1;
    const int row0  = blockIdx.x * TM;
    const int code0 = blockIdx.y * KC;

    if (t < 128) xsq_l[t] = xsq[row0 + t];
    colmin_l[t] = 0xFFFFFFFFu; colmin_l[t + 256] = 0xFFFFFFFFu;
#pragma unroll
    for (int i = 0; i < 16; ++i)
        u12_l[i][t] = make_uint2(0xFFFFFFFFu, 0xFFFFFFFFu);

    const unsigned short* abase =
        xh_g + ((size_t)(row0 + whalf * 64 + L) * DIM + quad * 8);

    // Staging (swizzled): LDS 16B-chunk j holds global (row j>>2,
    // slot (j&3)^((j>>3)&3)) -- slot t at row r carries global slot
    // t^((r>>1)&3), an involution. Linear LDS dest per DMA semantics.
    auto stageB = [&](int buf, int kt_, int dc_) {
        const unsigned short* bsrc =
            ch_g + (size_t)(code0 + kt_ * TN) * DIM + dc_ * BK;
        unsigned short* dst = &b_lds[buf][0][0];
#pragma unroll
        for (int k = 0; k < 2; ++k) {
            const int j = t + k * 256;
            const int r = j >> 2, sg = (j & 3) ^ ((j >> 3) & 3);
            GLOAD_LDS16(bsrc + (size_t)r * DIM + sg * 8, dst + (size_t)j * 8);
        }
    };

    const int bslot = (L >> 1) & 3;     // read-side swizzle term

    // prologue: first B slice in flight; A panel -> 32 persistent VGPR frags
    stageB(0, 0, 0);
    f16x8 afr[NDC][4];                  // 128 VGPRs, compile-time indexed
#pragma unroll
    for (int dc = 0; dc < NDC; ++dc)
#pragma unroll
        for (int mt = 0; mt < 4; ++mt)
            afr[dc][mt] = *(const f16x8*)(abase + (size_t)mt * 16 * DIM + dc * BK);

    for (int kt = 0; kt < NKT; ++kt) {
        const int cb0 = code0 + kt * TN;
        f32x4 acc[4][4];
#pragma unroll
        for (int mt = 0; mt < 4; ++mt)
#pragma unroll
            for (int nt = 0; nt < 4; ++nt) acc[mt][nt] = (f32x4){0.f, 0.f, 0.f, 0.f};

#pragma unroll
        for (int dc = 0; dc < NDC; ++dc) {
            const int cur = dc & 1;     // compile-time buffer parity
            __syncthreads();     // vmcnt(0) drain => buf[cur] staged; all
                                 // waves done reading buf[cur^1]
            if (!(kt == NKT - 1 && dc == NDC - 1))
                stageB(cur ^ 1, kt + (dc == NDC - 1), (dc + 1) & 7);

            f16x8 bf[4];
#pragma unroll
            for (int nt = 0; nt < 4; ++nt)
                bf[nt] = *(const f16x8*)
                    &b_lds[cur][chalf * 64 + nt * 16 + L][(quad ^ bslot) * 8];
#pragma unroll
            for (int mt = 0; mt < 4; ++mt)
#pragma unroll
                for (int nt = 0; nt < 4; ++nt)
                    acc[mt][nt] = __builtin_amdgcn_mfma_f32_16x16x32_f16(
                        afr[dc][mt], bf[nt], acc[mt][nt], 0, 0, 0);
        }

        // ---- epilogue: packed-key top-2 upkeep (LDS state) + column-min.
        // Overlaps the already-issued DMA of next kt's first slice.
        float csq4[4]; unsigned colf[4];
        float dmin[4] = {3.4e38f, 3.4e38f, 3.4e38f, 3.4e38f};
#pragma unroll
        for (int nt = 0; nt < 4; ++nt) {
            csq4[nt] = csq[cb0 + chalf * 64 + nt * 16 + L];
            colf[nt] = (unsigned)(kt * 128 + chalf * 64 + nt * 16 + L);
        }
#pragma unroll
        for (int mt = 0; mt < 4; ++mt) {
            const f32x4 xq = *(const f32x4*)&xsq_l[whalf * 64 + mt * 16 + quad * 4];
#pragma unroll
            for (int reg = 0; reg < 4; ++reg) {
                const int i = mt * 4 + reg;
                uint2 e = u12_l[i][t];
#pragma unroll
                for (int nt = 0; nt < 4; ++nt) {
                    float s = fmaf(-2.0f, acc[mt][nt][reg], csq4[nt]);
                    unsigned key = (fkey(s) & 0xFFFFFE00u) | colf[nt];
                    unsigned lo = umin_(e.x, key);
                    e.y = umin_(e.y, umax_(e.x, key));
                    e.x = lo;
                    dmin[nt] = fminf(dmin[nt], xq[reg] + s);
                }
                u12_l[i][t] = e;
            }
        }
#pragma unroll
        for (int nt = 0; nt < 4; ++nt) {
            unsigned dk = fkey(dmin[nt]);
            dk = umin_(dk, (unsigned)__shfl_xor((int)dk, 16));
            dk = umin_(dk, (unsigned)__shfl_xor((int)dk, 32));
            if (quad == 0)
                atomicMin(&colmin_l[kt * TN + chalf * 64 + nt * 16 + L], dk);
        }
    }

    // ---- once per block: butterfly-merge top-2 across the 16 L-lanes ----
    unsigned u1[16], u2[16];
#pragma unroll
    for (int i = 0; i < 16; ++i) {
        uint2 e = u12_l[i][t];
        u1[i] = e.x; u2[i] = e.y;
    }
#pragma unroll
    for (int i = 0; i < 16; ++i) {
#pragma unroll
        for (int st = 1; st < 16; st <<= 1) {
            unsigned w1 = (unsigned)__shfl_xor((int)u1[i], st);
            unsigned w2 = (unsigned)__shfl_xor((int)u2[i], st);
            unsigned a = umin_(u1[i], w1), b = umax_(u1[i], w1);
            u1[i] = a;
            u2[i] = umin_(umin_(u2[i], w2), b);
        }
    }
    if (L == 0) {
        const size_t gbase = (size_t)(blockIdx.y * 2 + chalf) * N_ROWS;
#pragma unroll
        for (int mt = 0; mt < 4; ++mt)
#pragma unroll
            for (int reg = 0; reg < 4; ++reg) {
                const int row = row0 + whalf * 64 + mt * 16 + quad * 4 + reg;
                top2_out[gbase + row] = make_uint2(u1[mt * 4 + reg], u2[mt * 4 + reg]);
            }
    }

    // ---- flush block-local colmin to private slice (plain stores) ----
    __syncthreads();
    unsigned* cp = colmin_part + (size_t)blockIdx.x * KCODES + code0;
    cp[t]       = colmin_l[t];
    cp[t + 256] = colmin_l[t + 256];
}

// ---- refine + gather + MSE, fused. grid = N_ROWS/4, 1 wave per row. ----
// R17: lane-parallel candidate selection (u64 key = score32|id32, same
// (v,id) lexicographic order). Fast path: (min1,min2) butterfly. Slow
// path: 8x extract-min recovers the identical top-8 set, then fp64
// re-score. R21: per-lane p[k]=cc2-2dd partials -> 9-value fp64 reduce.
__global__ __launch_bounds__(256) void vq_refine_kernel(
        const float* __restrict__ x, const float* __restrict__ cb,
        const uint2* __restrict__ top2, unsigned* __restrict__ active,
        float* __restrict__ out, double* __restrict__ accum) {
    __shared__ double wsum[4];
    const int wave = threadIdx.x >> 6, lane = threadIdx.x & 63;
    const int row  = blockIdx.x * 4 + wave;

    // lane-owned candidate -> packed u64 (quantized-score | id)
    const int g = (lane >> 1) & 15;
    uint2 e = top2[(size_t)g * N_ROWS + row];
    unsigned key = (lane & 1) ? e.y : e.x;
    unsigned idc = (unsigned)((g >> 1) * KC) + (key & 0x1FFu);
    unsigned long long pk =
        ((unsigned long long)(key & 0xFFFFFE00u) << 32) | idc;
    if (lane >= 32) pk = ~0ull;

    // butterfly (min1, min2) across 64 lanes -- wave-uniform result
    unsigned long long m1 = pk, m2 = ~0ull;
#pragma unroll
    for (int o = 1; o < 64; o <<= 1) {
        unsigned long long w1 = (unsigned long long)__shfl_xor((long long)m1, o);
        unsigned long long w2 = (unsigned long long)__shfl_xor((long long)m2, o);
        unsigned long long lo = umin64_(m1, w1), hi = umax64_(m1, w1);
        m1 = lo;
        m2 = umin64_(umin64_(m2, w2), hi);
    }
    const float v0 = fkey_inv((unsigned)(m1 >> 32));
    const float v1 = fkey_inv((unsigned)(m2 >> 32));

    float4 xv = ((const float4*)(x + (size_t)row * DIM))[lane];
    int tok;
    if (v1 > v0 + 1.0e-2f) {
        tok = (int)(unsigned)(m1 & 0xFFFFFFFFu);
    } else {
        // recover top-8 ids (ascending (v,id) order) by repeated extract-min
        int id8[8];
        unsigned long long cur = pk;
#pragma unroll
        for (int k = 0; k < 8; ++k) {
            unsigned long long m = cur;
#pragma unroll
            for (int o = 1; o < 64; o <<= 1)
                m = umin64_(m, (unsigned long long)__shfl_xor((long long)m, o));
            id8[k] = (int)(unsigned)(m & 0xFFFFFFFFu);
            if (cur == m) cur = ~0ull;   // owning lane removes it
        }

        double xs64 = (double)xv.x * xv.x + (double)xv.y * xv.y
                    + (double)xv.z * xv.z + (double)xv.w * xv.w;
        double p[8];
#pragma unroll
        for (int k = 0; k < 8; ++k) {
            float4 c4 = ((const float4*)(cb + (size_t)id8[k] * DIM))[lane];
            double dd  = (double)xv.x * c4.x + (double)xv.y * c4.y
                       + (double)xv.z * c4.z + (double)xv.w * c4.w;
            double cc2 = (double)c4.x * c4.x + (double)c4.y * c4.y
                       + (double)c4.z * c4.z + (double)c4.w * c4.w;
            p[k] = cc2 - 2.0 * dd;       // per-lane partial of cc2 - 2 x.c
        }
#pragma unroll
        for (int o = 32; o; o >>= 1) {
            xs64 += __shfl_down(xs64, o);
#pragma unroll
            for (int k = 0; k < 8; ++k)
                p[k] += __shfl_down(p[k], o);
        }
        if (lane == 0) {
            double D[8], Dmin = 1e300;
#pragma unroll
            for (int k = 0; k < 8; ++k) {
                D[k] = xs64 + p[k];
                Dmin = fmin(Dmin, D[k]);
            }
            int e2; frexp(Dmin, &e2);
            double U   = ldexp(1.0, e2 - 1 - 23);     // ulp_fp32(Dmin)
            double thr = Dmin + 0.75 * U;
            tok = 0x7FFFFFFF;
#pragma unroll
            for (int k = 0; k < 8; ++k)
                if (D[k] <= thr && id8[k] < tok) tok = id8[k];
        }
        tok = __shfl(tok, 0);
    }

    if (lane == 0) active[tok] = 1u;
    float4 sel = ((const float4*)(cb + (size_t)tok * DIM))[lane];
    ((float4*)out)[(size_t)row * 64 + lane] = sel;
    float dx = sel.x - xv.x, dy = sel.y - xv.y, dz = sel.z - xv.z, dw = sel.w - xv.w;
    float s = dx * dx + dy * dy + dz * dz + dw * dw;
    for (int o = 32; o; o >>= 1) s += __shfl_down(s, o);
    if (lane == 0) wsum[wave] = (double)s;
    __syncthreads();
    if (threadIdx.x == 0) atomicAdd(accum, wsum[0] + wsum[1] + wsum[2] + wsum[3]);
}

// ---- final: 128-way colmin reduction + entropy + loss. grid = 64 blocks.
// R22: 64 codes/block x 4-way rb split (coalesced 256B chunks), 4x the
// parallelism of the old 16-block version; 64th finisher computes loss.
__global__ __launch_bounds__(256) void vq_final_kernel(
        const unsigned* __restrict__ colmin_part, const unsigned* __restrict__ active,
        double* __restrict__ accum, unsigned* __restrict__ counter,
        float* __restrict__ out) {
    __shared__ unsigned pmin[4][64];
    __shared__ double red[64];
    const int t = threadIdx.x;
    const int cl = t & 63, part = t >> 6;     // 64 codes x 4 rb-parts
    const int c = blockIdx.x * 64 + cl;
    unsigned m = 0xFFFFFFFFu;
#pragma unroll 8
    for (int rb = part * 32; rb < part * 32 + 32; ++rb)
        m = umin_(m, colmin_part[(size_t)rb * KCODES + c]);
    pmin[part][cl] = m;
    __syncthreads();
    if (part == 0) {
        m = umin_(umin_(pmin[0][cl], pmin[1][cl]),
                  umin_(pmin[2][cl], pmin[3][cl]));
        red[cl] = (active[c] == 0u) ? (double)fkey_inv(m) : 0.0;
    }
    __syncthreads();
    if (t < 64) {
        double s = red[t];
        for (int o = 32; o; o >>= 1) s += __shfl_down(s, o);
        if (t == 0) {
            atomicAdd(&accum[1], s);
            __threadfence();
            unsigned old = atomicAdd(counter, 1u);
            if (old == 63u) {
                __threadfence();
                double ent = atomicAdd(&accum[1], 0.0);   // atomic read
                double loss = 1.25 * (accum[0] / (double)((size_t)N_ROWS * DIM))
                            + 0.02 * (ent / (double)KCODES);
                out[(size_t)N_ROWS * DIM] = (float)loss;
            }
        }
    }
}

extern "C" void kernel_launch(void* const* d_in, const int* in_sizes, int n_in,
                              void* d_out, int out_size, void* d_ws, size_t ws_size,
                              hipStream_t stream) {
    const float* x  = (const float*)d_in[0];   // [16384, 256]
    const float* cb = (const float*)d_in[1];   // [4096, 256]
    float* out = (float*)d_out;                // [16384*256] ++ [1] loss

    char* ws = (char*)d_ws;
    float*    xsq     = (float*)(ws + 0);                      // 64 KB
    float*    csq     = (float*)(ws + 65536);                  // 16 KB
    unsigned* active  = (unsigned*)(ws + 81920);               // 16 KB
    double*   accum   = (double*)(ws + 98304);                 // 256 B (mse, entropy)
    unsigned* counter = (unsigned*)(ws + 98560);               // 64 B
    uint2*    top2    = (uint2*)(ws + 131072);                 // 2 MB (16 granules)
    unsigned* cpart   = (unsigned*)(ws + 2228224);             // 2 MB (128 x 4096)
    unsigned short* xh_g = (unsigned short*)(ws + 4325376);    // 8 MB
    unsigned short* ch_g = (unsigned short*)(ws + 12713984);   // 2 MB (~14.2 MB)

    vq_prep_kernel<<<((N_ROWS + KCODES) * DIM) / 1024, 256, 0, stream>>>(
        x, cb, xh_g, ch_g, xsq, csq, active, accum, counter);
    vq_gemm_kernel<<<dim3(NRB, NCHUNK), 256, 0, stream>>>(
        xh_g, ch_g, xsq, csq, cpart, top2);
    vq_refine_kernel<<<N_ROWS / 4, 256, 0, stream>>>(
        x, cb, top2, active, out, accum);
    vq_final_kernel<<<KCODES / 64, 256, 0, stream>>>(
        cpart, active, accum, counter, out);
}